// Round 1
// baseline (1086.556 us; speedup 1.0000x reference)
//
#include <hip/hip_runtime.h>

// ---------------------------------------------------------------------------
// MLA forward for MI355X (gfx950). FP16 MFMA compute, f32 accumulate.
// SEQ=4096 EMBED=2048 H=16 QLR=512 KVLR=512 RD=64 VD=128 KD=192
// ---------------------------------------------------------------------------

#define SEQ   4096
#define EMBED 2048
#define NHEAD 16
#define QLR   512
#define KVLR  512
#define RD    64
#define VD    128
#define KDIM  192   // VD + RD

typedef __attribute__((ext_vector_type(8))) _Float16 half8;
typedef __attribute__((ext_vector_type(4))) float    f32x4;

// ---- staging loaders: 8 contiguous elements -> f16 ------------------------
__device__ inline half8 ld8_cvt(const float* p) {
    const float4 a = *reinterpret_cast<const float4*>(p);
    const float4 b = *reinterpret_cast<const float4*>(p + 4);
    half8 r;
    r[0] = (_Float16)a.x; r[1] = (_Float16)a.y; r[2] = (_Float16)a.z; r[3] = (_Float16)a.w;
    r[4] = (_Float16)b.x; r[5] = (_Float16)b.y; r[6] = (_Float16)b.z; r[7] = (_Float16)b.w;
    return r;
}
__device__ inline half8 ld8_cvt(const _Float16* p) {
    return *reinterpret_cast<const half8*>(p);
}

// ---------------------------------------------------------------------------
// Generic GEMM:  C[m][n] = sum_k A[m][k] * B[n][k]   (weights stored (N,K))
// 128x128 tile, BK=64, 4 waves, each wave owns a 64x64 sub-tile (4x4 frags).
// A/B fragments use the SAME per-lane k-slot mapping (8 contiguous at
// k=(lane>>4)*8), so any HW k-permutation cancels in the dot product.
// EPI: 0 plain f16 (ldc=N) | 1 q_content->q_final | 2 q_rope->q_final
//      3 kv split -> k_final,v | 4 plain f32 (ldc=N)
// ---------------------------------------------------------------------------
template <typename TA, typename TB, int EPI>
__global__ __launch_bounds__(256) void gemm_bt(const TA* __restrict__ A,
                                               const TB* __restrict__ B,
                                               void* __restrict__ out0,
                                               void* __restrict__ out1,
                                               int M, int N, int K)
{
    const int BK = 64;
    __shared__ _Float16 sA[128][72];   // +8 pad: 144B stride (16B-aligned, 2-way banks = free)
    __shared__ _Float16 sB[128][72];

    const int tid  = threadIdx.x;
    const int wid  = tid >> 6;
    const int lane = tid & 63;
    const int lr   = lane & 15;
    const int lg   = lane >> 4;
    const int row0 = blockIdx.y * 128;
    const int col0 = blockIdx.x * 128;
    const int war  = (wid >> 1) * 64;
    const int wac  = (wid & 1) * 64;

    f32x4 acc[4][4] = {};

    for (int k0 = 0; k0 < K; k0 += BK) {
        for (int c = tid; c < 1024; c += 256) {
            const int r  = c >> 3;
            const int kc = (c & 7) * 8;
            *reinterpret_cast<half8*>(&sA[r][kc]) =
                ld8_cvt(&A[(size_t)(row0 + r) * K + k0 + kc]);
            if (col0 + r < N) {
                *reinterpret_cast<half8*>(&sB[r][kc]) =
                    ld8_cvt(&B[(size_t)(col0 + r) * K + k0 + kc]);
            } else {
                half8 z = {};
                *reinterpret_cast<half8*>(&sB[r][kc]) = z;
            }
        }
        __syncthreads();

        for (int kk = 0; kk < BK; kk += 32) {
            half8 a[4], b[4];
#pragma unroll
            for (int i = 0; i < 4; ++i)
                a[i] = *reinterpret_cast<const half8*>(&sA[war + i * 16 + lr][kk + lg * 8]);
#pragma unroll
            for (int j = 0; j < 4; ++j)
                b[j] = *reinterpret_cast<const half8*>(&sB[wac + j * 16 + lr][kk + lg * 8]);
#pragma unroll
            for (int i = 0; i < 4; ++i)
#pragma unroll
                for (int j = 0; j < 4; ++j)
                    acc[i][j] = __builtin_amdgcn_mfma_f32_16x16x32_f16(a[i], b[j], acc[i][j], 0, 0, 0);
        }
        __syncthreads();
    }

    // C/D frag mapping: col = lane&15, row = (lane>>4)*4 + reg  [HW-verified]
#pragma unroll
    for (int i = 0; i < 4; ++i)
#pragma unroll
        for (int j = 0; j < 4; ++j)
#pragma unroll
            for (int r = 0; r < 4; ++r) {
                const int grow = row0 + war + i * 16 + lg * 4 + r;
                const int gcol = col0 + wac + j * 16 + lr;
                if (gcol >= N || grow >= M) continue;
                const float v = acc[i][j][r];
                if constexpr (EPI == 0) {
                    ((_Float16*)out0)[(size_t)grow * N + gcol] = (_Float16)v;
                } else if constexpr (EPI == 1) {
                    ((_Float16*)out0)[(size_t)grow * (NHEAD * KDIM) + (gcol >> 7) * KDIM + (gcol & 127)] = (_Float16)v;
                } else if constexpr (EPI == 2) {
                    ((_Float16*)out0)[(size_t)grow * (NHEAD * KDIM) + (gcol >> 6) * KDIM + VD + (gcol & 63)] = (_Float16)v;
                } else if constexpr (EPI == 3) {
                    if (gcol < NHEAD * VD)
                        ((_Float16*)out0)[(size_t)grow * (NHEAD * KDIM) + (gcol >> 7) * KDIM + (gcol & 127)] = (_Float16)v;
                    else
                        ((_Float16*)out1)[(size_t)grow * (NHEAD * VD) + (gcol - NHEAD * VD)] = (_Float16)v;
                } else {
                    ((float*)out0)[(size_t)grow * N + gcol] = v;
                }
            }
}

// ---------------------------------------------------------------------------
// RoPE: rotate q_final[..][h*192+128..191] in place; rotate shared k_rope and
// broadcast into all heads' k_final rope slots. sin/cos computed in f64 once
// per (s,i) into LDS (tiny cost, removes trig error from the tolerance budget).
// ---------------------------------------------------------------------------
__global__ __launch_bounds__(256) void rope_kernel(_Float16* __restrict__ qf,
                                                   _Float16* __restrict__ kf,
                                                   const _Float16* __restrict__ ktmp)
{
    __shared__ float s_sin[32], s_cos[32];
    const int s   = blockIdx.x;
    const int tid = threadIdx.x;
    if (tid < 32) {
        const double inv = exp(-(double)tid * (log(10000.0) / 32.0));
        const double ang = (double)s * inv;
        s_sin[tid] = (float)sin(ang);
        s_cos[tid] = (float)cos(ang);
    }
    __syncthreads();

    for (int p = tid; p < NHEAD * 32; p += 256) {
        const int h = p >> 5, i = p & 31;
        const size_t base = (size_t)s * (NHEAD * KDIM) + h * KDIM + VD;
        const float x1 = (float)qf[base + i];
        const float x2 = (float)qf[base + 32 + i];
        const float cs = s_cos[i], sn = s_sin[i];
        qf[base + i]      = (_Float16)(x1 * cs - x2 * sn);
        qf[base + 32 + i] = (_Float16)(x2 * cs + x1 * sn);
    }
    if (tid < 32) {
        const int i = tid;
        const float x1 = (float)ktmp[(size_t)s * RD + i];
        const float x2 = (float)ktmp[(size_t)s * RD + 32 + i];
        const float cs = s_cos[i], sn = s_sin[i];
        const _Float16 r1 = (_Float16)(x1 * cs - x2 * sn);
        const _Float16 r2 = (_Float16)(x2 * cs + x1 * sn);
#pragma unroll
        for (int h = 0; h < NHEAD; ++h) {
            const size_t base = (size_t)s * (NHEAD * KDIM) + h * KDIM + VD;
            kf[base + i]      = r1;
            kf[base + 32 + i] = r2;
        }
    }
}

// ---------------------------------------------------------------------------
// Flash attention (causal). Block = (head, 64 q rows), 4 waves x 16 rows each.
// K tile (64x192) and V^T (128x[64+8]) staged in LDS per KV step. Online
// softmax in registers. P goes C-frag -> per-wave LDS -> A-frag with the same
// contiguous-j k-mapping used for V^T fragments (permutation-consistent).
// ---------------------------------------------------------------------------
__global__ __launch_bounds__(256) void fattn(const _Float16* __restrict__ qf,
                                             const _Float16* __restrict__ kf,
                                             const _Float16* __restrict__ vf,
                                             _Float16* __restrict__ attn)
{
    __shared__ _Float16 sK[64][200];
    __shared__ _Float16 sVt[128][72];
    __shared__ _Float16 sP[4][16][72];

    const int qt = gridDim.x - 1 - blockIdx.x;   // biggest blocks first
    const int h  = blockIdx.y;
    const int q0 = qt * 64;

    const int tid  = threadIdx.x;
    const int wid  = tid >> 6;
    const int lane = tid & 63;
    const int lr   = lane & 15;
    const int lg   = lane >> 4;

    half8 qfr[6];
    {
        const int qrow = q0 + wid * 16 + lr;
        const _Float16* qbase = qf + (size_t)qrow * (NHEAD * KDIM) + h * KDIM + lg * 8;
#pragma unroll
        for (int kk = 0; kk < 6; ++kk)
            qfr[kk] = *reinterpret_cast<const half8*>(qbase + kk * 32);
    }

    f32x4 o[8] = {};
    float m_r[4], l_r[4];
#pragma unroll
    for (int r = 0; r < 4; ++r) { m_r[r] = -1e30f; l_r[r] = 0.0f; }
    const float scale = 1.0f / sqrtf((float)KDIM);

    for (int t = 0; t <= qt; ++t) {
        const int j0 = t * 64;
        for (int c = tid; c < 1536; c += 256) {
            const int r  = c / 24;
            const int kc = (c % 24) * 8;
            *reinterpret_cast<half8*>(&sK[r][kc]) =
                *reinterpret_cast<const half8*>(kf + (size_t)(j0 + r) * (NHEAD * KDIM) + h * KDIM + kc);
        }
        for (int c = tid; c < 1024; c += 256) {
            const int j = c & 63;
            const int d = (c >> 6) * 8;
            const half8 vv = *reinterpret_cast<const half8*>(
                vf + (size_t)(j0 + j) * (NHEAD * VD) + h * VD + d);
#pragma unroll
            for (int e = 0; e < 8; ++e) sVt[d + e][j] = vv[e];
        }
        __syncthreads();

        f32x4 s[4];
#pragma unroll
        for (int jt = 0; jt < 4; ++jt) {
            f32x4 a = {};
#pragma unroll
            for (int kk = 0; kk < 6; ++kk) {
                const half8 b = *reinterpret_cast<const half8*>(&sK[jt * 16 + lr][kk * 32 + lg * 8]);
                a = __builtin_amdgcn_mfma_f32_16x16x32_f16(qfr[kk], b, a, 0, 0, 0);
            }
            s[jt] = a;
        }

        const int qrow_g = q0 + wid * 16 + lg * 4;   // + r
        float rmax[4];
#pragma unroll
        for (int r = 0; r < 4; ++r) rmax[r] = -1e30f;
#pragma unroll
        for (int jt = 0; jt < 4; ++jt) {
            const int jg = j0 + jt * 16 + lr;
#pragma unroll
            for (int r = 0; r < 4; ++r) {
                float v = s[jt][r] * scale;
                if (jg > qrow_g + r) v = -1e30f;
                s[jt][r] = v;
                rmax[r] = fmaxf(rmax[r], v);
            }
        }
#pragma unroll
        for (int r = 0; r < 4; ++r)
            for (int msk = 1; msk < 16; msk <<= 1)
                rmax[r] = fmaxf(rmax[r], __shfl_xor(rmax[r], msk, 64));

        float alpha[4], rsum[4];
#pragma unroll
        for (int r = 0; r < 4; ++r) {
            const float mn = fmaxf(m_r[r], rmax[r]);
            alpha[r] = __expf(m_r[r] - mn);
            m_r[r] = mn;
            rsum[r] = 0.0f;
        }
#pragma unroll
        for (int jt = 0; jt < 4; ++jt)
#pragma unroll
            for (int r = 0; r < 4; ++r) {
                const float p = __expf(s[jt][r] - m_r[r]);
                s[jt][r] = p;
                rsum[r] += p;
            }
#pragma unroll
        for (int r = 0; r < 4; ++r) {
            for (int msk = 1; msk < 16; msk <<= 1)
                rsum[r] += __shfl_xor(rsum[r], msk, 64);
            l_r[r] = l_r[r] * alpha[r] + rsum[r];
        }
#pragma unroll
        for (int dt = 0; dt < 8; ++dt)
#pragma unroll
            for (int r = 0; r < 4; ++r) o[dt][r] *= alpha[r];

#pragma unroll
        for (int jt = 0; jt < 4; ++jt)
#pragma unroll
            for (int r = 0; r < 4; ++r)
                sP[wid][lg * 4 + r][jt * 16 + lr] = (_Float16)s[jt][r];
        asm volatile("s_waitcnt lgkmcnt(0)" ::: "memory");

#pragma unroll
        for (int kk = 0; kk < 2; ++kk) {
            const half8 pa = *reinterpret_cast<const half8*>(&sP[wid][lr][kk * 32 + lg * 8]);
#pragma unroll
            for (int dt = 0; dt < 8; ++dt) {
                const half8 bv = *reinterpret_cast<const half8*>(&sVt[dt * 16 + lr][kk * 32 + lg * 8]);
                o[dt] = __builtin_amdgcn_mfma_f32_16x16x32_f16(pa, bv, o[dt], 0, 0, 0);
            }
        }
        __syncthreads();
    }

#pragma unroll
    for (int r = 0; r < 4; ++r) {
        const float inv_l = 1.0f / l_r[r];
        const int grow = q0 + wid * 16 + lg * 4 + r;
#pragma unroll
        for (int dt = 0; dt < 8; ++dt)
            attn[(size_t)grow * (NHEAD * VD) + h * VD + dt * 16 + lr] =
                (_Float16)(o[dt][r] * inv_l);
    }
}

// ---------------------------------------------------------------------------
extern "C" void kernel_launch(void* const* d_in, const int* in_sizes, int n_in,
                              void* d_out, int out_size, void* d_ws, size_t ws_size,
                              hipStream_t stream)
{
    (void)in_sizes; (void)n_in; (void)out_size; (void)ws_size;
    const float* x    = (const float*)d_in[0];
    // d_in[1] = causal mask (tril) — known analytically, ignored
    const float* wqd  = (const float*)d_in[2];
    const float* wqu  = (const float*)d_in[3];
    const float* wqr  = (const float*)d_in[4];
    const float* wkvd = (const float*)d_in[5];
    const float* wkvu = (const float*)d_in[6];
    const float* wkr  = (const float*)d_in[7];
    const float* wout = (const float*)d_in[8];
    float* out = (float*)d_out;

    char* ws = (char*)d_ws;
    _Float16* c_q  = (_Float16*)ws; ws += (size_t)SEQ * QLR * 2;
    _Float16* c_kv = (_Float16*)ws; ws += (size_t)SEQ * KVLR * 2;
    _Float16* qfin = (_Float16*)ws; ws += (size_t)SEQ * NHEAD * KDIM * 2;
    _Float16* kfin = (_Float16*)ws; ws += (size_t)SEQ * NHEAD * KDIM * 2;
    _Float16* vbuf = (_Float16*)ws; ws += (size_t)SEQ * NHEAD * VD * 2;
    _Float16* ktmp = (_Float16*)ws; ws += (size_t)SEQ * RD * 2;
    _Float16* attn = (_Float16*)ws; ws += (size_t)SEQ * NHEAD * VD * 2;

    dim3 blk(256);

    // 1) c_q = x @ w_q_down^T            (4096x512,  K=2048)
    gemm_bt<float, float, 0><<<dim3(QLR / 128, SEQ / 128), blk, 0, stream>>>(
        x, wqd, c_q, nullptr, SEQ, QLR, EMBED);
    // 2) c_kv = x @ w_kv_down^T          (4096x512,  K=2048)
    gemm_bt<float, float, 0><<<dim3(KVLR / 128, SEQ / 128), blk, 0, stream>>>(
        x, wkvd, c_kv, nullptr, SEQ, KVLR, EMBED);
    // 3) k_rope_shared = x @ w_k_rope^T  (4096x64,   K=2048)
    gemm_bt<float, float, 0><<<dim3(1, SEQ / 128), blk, 0, stream>>>(
        x, wkr, ktmp, nullptr, SEQ, RD, EMBED);
    // 4) q_content -> q_final            (4096x2048, K=512)
    gemm_bt<_Float16, float, 1><<<dim3((NHEAD * VD) / 128, SEQ / 128), blk, 0, stream>>>(
        c_q, wqu, qfin, nullptr, SEQ, NHEAD * VD, QLR);
    // 5) q_rope -> q_final               (4096x1024, K=512)
    gemm_bt<_Float16, float, 2><<<dim3((NHEAD * RD) / 128, SEQ / 128), blk, 0, stream>>>(
        c_q, wqr, qfin, nullptr, SEQ, NHEAD * RD, QLR);
    // 6) kv -> k_final, v                (4096x4096, K=512)
    gemm_bt<_Float16, float, 3><<<dim3((NHEAD * 2 * VD) / 128, SEQ / 128), blk, 0, stream>>>(
        c_kv, wkvu, kfin, vbuf, SEQ, NHEAD * 2 * VD, KVLR);
    // 7) RoPE (q in place + k broadcast)
    rope_kernel<<<dim3(SEQ), blk, 0, stream>>>(qfin, kfin, ktmp);
    // 8) causal flash attention
    fattn<<<dim3(SEQ / 64, NHEAD), blk, 0, stream>>>(qfin, kfin, vbuf, attn);
    // 9) out = attn @ w_out^T            (4096x2048, K=2048, f32 out)
    gemm_bt<_Float16, float, 4><<<dim3(EMBED / 128, SEQ / 128), blk, 0, stream>>>(
        attn, wout, out, nullptr, SEQ, EMBED, NHEAD * VD);
}

// Round 2
// 998.786 us; speedup vs baseline: 1.0879x; 1.0879x over previous
//
#include <hip/hip_runtime.h>

// ---------------------------------------------------------------------------
// MLA forward, MI355X (gfx950). FP16 MFMA, f32 accumulate.
// SEQ=4096 EMBED=2048 H=16 QLR=512 KVLR=512 RD=64 VD=128 KD=192
// Round 2: f16 pre-conversion + global_load_lds GEMMs (m97 structure),
//          fused GEMMs (4 total), V pre-transposed, dual-q-tile flash attn.
// ---------------------------------------------------------------------------

#define SEQ   4096
#define EMBED 2048
#define NHEAD 16
#define QLR   512
#define KVLR  512
#define RD    64
#define VD    128
#define KDIM  192

typedef __attribute__((ext_vector_type(8))) _Float16 half8;
typedef __attribute__((ext_vector_type(4))) _Float16 half4;
typedef __attribute__((ext_vector_type(4))) float    f32x4;

// async global->LDS, 16B per lane; lds base must be wave-uniform.
__device__ __forceinline__ void gload16(void* lds, const void* g) {
    __builtin_amdgcn_global_load_lds(
        (const __attribute__((address_space(1))) void*)g,
        (__attribute__((address_space(3))) void*)lds, 16, 0, 0);
}

// ---------------- f32 -> f16 conversion kernels ----------------------------
__global__ __launch_bounds__(256) void cvt_plain(const float* __restrict__ s,
                                                 _Float16* __restrict__ d, int n8) {
    const int i = blockIdx.x * 256 + threadIdx.x;
    if (i >= n8) return;
    const float4 a = reinterpret_cast<const float4*>(s)[i * 2];
    const float4 b = reinterpret_cast<const float4*>(s)[i * 2 + 1];
    half8 r;
    r[0] = (_Float16)a.x; r[1] = (_Float16)a.y; r[2] = (_Float16)a.z; r[3] = (_Float16)a.w;
    r[4] = (_Float16)b.x; r[5] = (_Float16)b.y; r[6] = (_Float16)b.z; r[7] = (_Float16)b.w;
    reinterpret_cast<half8*>(d)[i] = r;
}

// concat [wqd(512); wkvd(512); wkr(64); zeros(64)] -> [1152][2048] f16
__global__ __launch_bounds__(256) void cvt_down(const float* __restrict__ wqd,
                                                const float* __restrict__ wkvd,
                                                const float* __restrict__ wkr,
                                                _Float16* __restrict__ dst) {
    const int i = blockIdx.x * 256 + threadIdx.x;          // 294912 chunks
    if (i >= 1152 * 2048 / 8) return;
    const int e = i * 8, row = e >> 11, col = e & 2047;
    const float* src = row < 512  ? wqd  + (size_t)row * 2048 + col
                     : row < 1024 ? wkvd + (size_t)(row - 512) * 2048 + col
                     : row < 1088 ? wkr  + (size_t)(row - 1024) * 2048 + col
                                  : nullptr;
    half8 r = {};
    if (src) {
        const float4 a = reinterpret_cast<const float4*>(src)[0];
        const float4 b = reinterpret_cast<const float4*>(src)[1];
        r[0] = (_Float16)a.x; r[1] = (_Float16)a.y; r[2] = (_Float16)a.z; r[3] = (_Float16)a.w;
        r[4] = (_Float16)b.x; r[5] = (_Float16)b.y; r[6] = (_Float16)b.z; r[7] = (_Float16)b.w;
    }
    reinterpret_cast<half8*>(dst)[i] = r;
}

// concat [wqu(2048); wqr(1024)] -> [3072][512] f16
__global__ __launch_bounds__(256) void cvt_qup(const float* __restrict__ wqu,
                                               const float* __restrict__ wqr,
                                               _Float16* __restrict__ dst) {
    const int i = blockIdx.x * 256 + threadIdx.x;          // 196608 chunks
    if (i >= 3072 * 512 / 8) return;
    const int e = i * 8, row = e >> 9, col = e & 511;
    const float* src = row < 2048 ? wqu + (size_t)row * 512 + col
                                  : wqr + (size_t)(row - 2048) * 512 + col;
    const float4 a = reinterpret_cast<const float4*>(src)[0];
    const float4 b = reinterpret_cast<const float4*>(src)[1];
    half8 r;
    r[0] = (_Float16)a.x; r[1] = (_Float16)a.y; r[2] = (_Float16)a.z; r[3] = (_Float16)a.w;
    r[4] = (_Float16)b.x; r[5] = (_Float16)b.y; r[6] = (_Float16)b.z; r[7] = (_Float16)b.w;
    reinterpret_cast<half8*>(dst)[i] = r;
}

// ---------------------------------------------------------------------------
// f16 GEMM, m97 structure: 128x128 tile, BK=64, 4 waves, global_load_lds x16.
// C[m][n] = sum_k A[m][k] * B[n][k].  M,N multiples of 128, K of 64.
// EPI 0: split -> c_q(512) | c_kv(512) | ktmp(64) | skip(64)
// EPI 1: q up  -> qfin (content cols<2048, rope otherwise)
// EPI 2: kv    -> kfin (cols<2048) | vT[h][d][s] packed (else)
// EPI 3: f32 plain -> of
// ---------------------------------------------------------------------------
template <int EPI>
__global__ __launch_bounds__(256) void gemm_f16(const _Float16* __restrict__ A,
                                                const _Float16* __restrict__ B,
                                                _Float16* __restrict__ o0,
                                                _Float16* __restrict__ o1,
                                                _Float16* __restrict__ o2,
                                                float* __restrict__ of,
                                                int M, int N, int K)
{
    __shared__ _Float16 sA[128 * 64];
    __shared__ _Float16 sB[128 * 64];

    const int tid  = threadIdx.x;
    const int wid  = tid >> 6;
    const int lane = tid & 63;
    const int lr   = lane & 15;
    const int lg   = lane >> 4;
    const int row0 = blockIdx.y * 128;
    const int col0 = blockIdx.x * 128;
    const int war  = (wid >> 1) * 64;
    const int wac  = (wid & 1) * 64;

    // staging: chunk c = i*4+wid writes LDS [c*1024 .. +1024); lane l covers
    // elements c*512 + l*8  ->  row = c*8 + (l>>3), col = (l&7)*8
    const int sr = lane >> 3;
    const int sk = (lane & 7) * 8;
    const _Float16* Ab = A + (size_t)(row0 + wid * 8 + sr) * K + sk;
    const _Float16* Bb = B + (size_t)(col0 + wid * 8 + sr) * K + sk;

    f32x4 acc[4][4] = {};

    for (int k0 = 0; k0 < K; k0 += 64) {
#pragma unroll
        for (int i = 0; i < 4; ++i) {
            const int c = i * 4 + wid;
            gload16((char*)sA + c * 1024, Ab + (size_t)i * 32 * K + k0);
            gload16((char*)sB + c * 1024, Bb + (size_t)i * 32 * K + k0);
        }
        __syncthreads();   // drains vmcnt (compiler emits the waitcnt)

#pragma unroll
        for (int kk = 0; kk < 64; kk += 32) {
            half8 a[4], b[4];
#pragma unroll
            for (int i = 0; i < 4; ++i)
                a[i] = *reinterpret_cast<const half8*>(&sA[(war + i * 16 + lr) * 64 + kk + lg * 8]);
#pragma unroll
            for (int j = 0; j < 4; ++j)
                b[j] = *reinterpret_cast<const half8*>(&sB[(wac + j * 16 + lr) * 64 + kk + lg * 8]);
            __builtin_amdgcn_s_setprio(1);
#pragma unroll
            for (int i = 0; i < 4; ++i)
#pragma unroll
                for (int j = 0; j < 4; ++j)
                    acc[i][j] = __builtin_amdgcn_mfma_f32_16x16x32_f16(a[i], b[j], acc[i][j], 0, 0, 0);
            __builtin_amdgcn_s_setprio(0);
        }
        __syncthreads();
    }

    // C/D mapping: col = lane&15, row = (lane>>4)*4 + reg
#pragma unroll
    for (int i = 0; i < 4; ++i)
#pragma unroll
        for (int j = 0; j < 4; ++j) {
            const int grow0 = row0 + war + i * 16 + lg * 4;
            const int gcol  = col0 + wac + j * 16 + lr;
            if constexpr (EPI == 2) {
                if (gcol >= 2048) {   // V region: pack 4 consecutive s, fixed d
                    half4 pv;
#pragma unroll
                    for (int r = 0; r < 4; ++r) pv[r] = (_Float16)acc[i][j][r];
                    *reinterpret_cast<half4*>(&o1[(size_t)(gcol - 2048) * SEQ + grow0]) = pv;
                    continue;
                }
            }
#pragma unroll
            for (int r = 0; r < 4; ++r) {
                const int grow = grow0 + r;
                const float v = acc[i][j][r];
                if constexpr (EPI == 0) {
                    if (gcol < 512)       o0[(size_t)grow * 512 + gcol] = (_Float16)v;
                    else if (gcol < 1024) o1[(size_t)grow * 512 + gcol - 512] = (_Float16)v;
                    else if (gcol < 1088) o2[(size_t)grow * 64 + gcol - 1024] = (_Float16)v;
                } else if constexpr (EPI == 1) {
                    if (gcol < 2048)
                        o0[(size_t)grow * (NHEAD * KDIM) + (gcol >> 7) * KDIM + (gcol & 127)] = (_Float16)v;
                    else {
                        const int c = gcol - 2048;
                        o0[(size_t)grow * (NHEAD * KDIM) + (c >> 6) * KDIM + VD + (c & 63)] = (_Float16)v;
                    }
                } else if constexpr (EPI == 2) {
                    o0[(size_t)grow * (NHEAD * KDIM) + (gcol >> 7) * KDIM + (gcol & 127)] = (_Float16)v;
                } else {
                    of[(size_t)grow * N + gcol] = v;
                }
            }
        }
}

// ---------------------------------------------------------------------------
// RoPE: q in place; shared k broadcast into all heads' rope slots of kfin.
// ---------------------------------------------------------------------------
__global__ __launch_bounds__(256) void rope_kernel(_Float16* __restrict__ qf,
                                                   _Float16* __restrict__ kf,
                                                   const _Float16* __restrict__ ktmp)
{
    __shared__ float s_sin[32], s_cos[32];
    const int s   = blockIdx.x;
    const int tid = threadIdx.x;
    if (tid < 32) {
        const double inv = exp(-(double)tid * (log(10000.0) / 32.0));
        const double ang = (double)s * inv;
        s_sin[tid] = (float)sin(ang);
        s_cos[tid] = (float)cos(ang);
    }
    __syncthreads();

    for (int p = tid; p < NHEAD * 32; p += 256) {
        const int h = p >> 5, i = p & 31;
        const size_t base = (size_t)s * (NHEAD * KDIM) + h * KDIM + VD;
        const float x1 = (float)qf[base + i];
        const float x2 = (float)qf[base + 32 + i];
        const float cs = s_cos[i], sn = s_sin[i];
        qf[base + i]      = (_Float16)(x1 * cs - x2 * sn);
        qf[base + 32 + i] = (_Float16)(x2 * cs + x1 * sn);
    }
    if (tid < 32) {
        const int i = tid;
        const float x1 = (float)ktmp[(size_t)s * RD + i];
        const float x2 = (float)ktmp[(size_t)s * RD + 32 + i];
        const float cs = s_cos[i], sn = s_sin[i];
        const _Float16 r1 = (_Float16)(x1 * cs - x2 * sn);
        const _Float16 r2 = (_Float16)(x2 * cs + x1 * sn);
#pragma unroll
        for (int h = 0; h < NHEAD; ++h) {
            const size_t base = (size_t)s * (NHEAD * KDIM) + h * KDIM + VD;
            kf[base + i]      = r1;
            kf[base + 32 + i] = r2;
        }
    }
}

// ---------------------------------------------------------------------------
// Dual-q-tile causal flash attention.
// Block = (pair p, head): q-tiles qtA=p and qtB=63-p (64 rows each).
// 4 waves; wave w owns rows w*16..+15 of BOTH tiles. Work per block is
// uniform (65 tile-consumptions) -> perfect balance, all 512 blocks resident.
// K-frag and V-frag LDS reads are shared by both tiles' MFMAs (2x reuse).
// ---------------------------------------------------------------------------
__global__ __launch_bounds__(256) void fattn(const _Float16* __restrict__ qf,
                                             const _Float16* __restrict__ kf,
                                             const _Float16* __restrict__ vT,
                                             _Float16* __restrict__ attn)
{
    __shared__ _Float16 sK[64][200];        // 192 + 8 pad
    __shared__ _Float16 sVt[128][72];       // from vT: row d, 64 j + 8 pad
    __shared__ _Float16 sP[2][4][16][72];   // [tile][wave]

    const int p  = blockIdx.x;              // 0..31
    const int h  = blockIdx.y;
    const int qt_[2] = { p, 63 - p };

    const int tid  = threadIdx.x;
    const int wid  = tid >> 6;
    const int lane = tid & 63;
    const int lr   = lane & 15;
    const int lg   = lane >> 4;

    const float scale = 0.0721687836487032f;   // 1/sqrt(192)

    half8 qfr[2][6];
#pragma unroll
    for (int tt = 0; tt < 2; ++tt) {
        const int qrow = qt_[tt] * 64 + wid * 16 + lr;
        const _Float16* qb = qf + (size_t)qrow * (NHEAD * KDIM) + h * KDIM + lg * 8;
#pragma unroll
        for (int kk = 0; kk < 6; ++kk)
            qfr[tt][kk] = *reinterpret_cast<const half8*>(qb + kk * 32);
    }

    f32x4 o[2][8] = {};
    float m_[2][4], l_[2][4];
#pragma unroll
    for (int tt = 0; tt < 2; ++tt)
#pragma unroll
        for (int r = 0; r < 4; ++r) { m_[tt][r] = -1e30f; l_[tt][r] = 0.0f; }

    for (int t = 0; t <= qt_[1]; ++t) {
        const bool actA = (t <= qt_[0]);
        const int j0 = t * 64;

        // ---- stage K tile 64x192 ----
        for (int c = tid; c < 1536; c += 256) {
            const int r  = c / 24;
            const int kc = (c % 24) * 8;
            *reinterpret_cast<half8*>(&sK[r][kc]) =
                *reinterpret_cast<const half8*>(kf + (size_t)(j0 + r) * (NHEAD * KDIM) + h * KDIM + kc);
        }
        // ---- stage V^T 128x64 from vT (vector everywhere) ----
        for (int c = tid; c < 1024; c += 256) {
            const int d  = c >> 3;
            const int j8 = (c & 7) * 8;
            *reinterpret_cast<half8*>(&sVt[d][j8]) =
                *reinterpret_cast<const half8*>(vT + (size_t)(h * VD + d) * SEQ + j0 + j8);
        }
        __syncthreads();

        // ---- S = Q K^T for both tiles, K-frag read once ----
        f32x4 s2[2][4];
        __builtin_amdgcn_s_setprio(1);
#pragma unroll
        for (int jt = 0; jt < 4; ++jt) {
            f32x4 aA = {}, aB = {};
#pragma unroll
            for (int kk = 0; kk < 6; ++kk) {
                const half8 bK = *reinterpret_cast<const half8*>(&sK[jt * 16 + lr][kk * 32 + lg * 8]);
                aB = __builtin_amdgcn_mfma_f32_16x16x32_f16(qfr[1][kk], bK, aB, 0, 0, 0);
                if (actA) aA = __builtin_amdgcn_mfma_f32_16x16x32_f16(qfr[0][kk], bK, aA, 0, 0, 0);
            }
            s2[0][jt] = aA; s2[1][jt] = aB;
        }
        __builtin_amdgcn_s_setprio(0);

        // ---- softmax per tile (mask only on the diagonal stage) ----
#pragma unroll
        for (int tt = 0; tt < 2; ++tt) {
            if (tt == 0 && !actA) continue;
            const int qrow_g = qt_[tt] * 64 + wid * 16 + lg * 4;
            const bool diag = (t == qt_[tt]);
            float rmax[4];
#pragma unroll
            for (int r = 0; r < 4; ++r) rmax[r] = -1e30f;
#pragma unroll
            for (int jt = 0; jt < 4; ++jt) {
                const int jg = j0 + jt * 16 + lr;
#pragma unroll
                for (int r = 0; r < 4; ++r) {
                    float v = s2[tt][jt][r] * scale;
                    if (diag && jg > qrow_g + r) v = -1e30f;
                    s2[tt][jt][r] = v;
                    rmax[r] = fmaxf(rmax[r], v);
                }
            }
#pragma unroll
            for (int r = 0; r < 4; ++r)
                for (int msk = 1; msk < 16; msk <<= 1)
                    rmax[r] = fmaxf(rmax[r], __shfl_xor(rmax[r], msk, 64));

            float alpha[4], rsum[4];
#pragma unroll
            for (int r = 0; r < 4; ++r) {
                const float mn = fmaxf(m_[tt][r], rmax[r]);
                alpha[r] = __expf(m_[tt][r] - mn);
                m_[tt][r] = mn;
                rsum[r] = 0.0f;
            }
#pragma unroll
            for (int jt = 0; jt < 4; ++jt)
#pragma unroll
                for (int r = 0; r < 4; ++r) {
                    const float pv = __expf(s2[tt][jt][r] - m_[tt][r]);
                    s2[tt][jt][r] = pv;
                    rsum[r] += pv;
                }
#pragma unroll
            for (int r = 0; r < 4; ++r) {
                for (int msk = 1; msk < 16; msk <<= 1)
                    rsum[r] += __shfl_xor(rsum[r], msk, 64);
                l_[tt][r] = l_[tt][r] * alpha[r] + rsum[r];
            }
#pragma unroll
            for (int dt = 0; dt < 8; ++dt)
#pragma unroll
                for (int r = 0; r < 4; ++r) o[tt][dt][r] *= alpha[r];

#pragma unroll
            for (int jt = 0; jt < 4; ++jt)
#pragma unroll
                for (int r = 0; r < 4; ++r)
                    sP[tt][wid][lg * 4 + r][jt * 16 + lr] = (_Float16)s2[tt][jt][r];
        }
        asm volatile("s_waitcnt lgkmcnt(0)" ::: "memory");
        __builtin_amdgcn_sched_barrier(0);

        // ---- O += P V, V-frag read once for both tiles ----
        __builtin_amdgcn_s_setprio(1);
#pragma unroll
        for (int kk = 0; kk < 2; ++kk) {
            const half8 paB = *reinterpret_cast<const half8*>(&sP[1][wid][lr][kk * 32 + lg * 8]);
            half8 paA = {};
            if (actA) paA = *reinterpret_cast<const half8*>(&sP[0][wid][lr][kk * 32 + lg * 8]);
#pragma unroll
            for (int dt = 0; dt < 8; ++dt) {
                const half8 bv = *reinterpret_cast<const half8*>(&sVt[dt * 16 + lr][kk * 32 + lg * 8]);
                o[1][dt] = __builtin_amdgcn_mfma_f32_16x16x32_f16(paB, bv, o[1][dt], 0, 0, 0);
                if (actA) o[0][dt] = __builtin_amdgcn_mfma_f32_16x16x32_f16(paA, bv, o[0][dt], 0, 0, 0);
            }
        }
        __builtin_amdgcn_s_setprio(0);
        __syncthreads();
    }

    // ---- normalize + store both tiles ----
#pragma unroll
    for (int tt = 0; tt < 2; ++tt)
#pragma unroll
        for (int r = 0; r < 4; ++r) {
            const float inv_l = 1.0f / l_[tt][r];
            const int grow = qt_[tt] * 64 + wid * 16 + lg * 4 + r;
#pragma unroll
            for (int dt = 0; dt < 8; ++dt)
                attn[(size_t)grow * (NHEAD * VD) + h * VD + dt * 16 + lr] =
                    (_Float16)(o[tt][dt][r] * inv_l);
        }
}

// ---------------------------------------------------------------------------
extern "C" void kernel_launch(void* const* d_in, const int* in_sizes, int n_in,
                              void* d_out, int out_size, void* d_ws, size_t ws_size,
                              hipStream_t stream)
{
    (void)in_sizes; (void)n_in; (void)out_size; (void)ws_size;
    const float* x    = (const float*)d_in[0];
    // d_in[1] = tril mask, known analytically -> ignored
    const float* wqd  = (const float*)d_in[2];
    const float* wqu  = (const float*)d_in[3];
    const float* wqr  = (const float*)d_in[4];
    const float* wkvd = (const float*)d_in[5];
    const float* wkvu = (const float*)d_in[6];
    const float* wkr  = (const float*)d_in[7];
    const float* wout = (const float*)d_in[8];
    float* out = (float*)d_out;

    // workspace (100 MB, with aliasing): x_h dead after G1 -> attn reuses it;
    // c_q/c_kv dead after G2/G3 -> wout_h reuses them (cvt_out runs after G3).
    char* ws = (char*)d_ws;
    _Float16* x_h    = (_Float16*)ws; ws += (size_t)SEQ * EMBED * 2;        // 16.8 MB
    _Float16* wdownh = (_Float16*)ws; ws += (size_t)1152 * EMBED * 2;       //  4.7 MB
    _Float16* wquph  = (_Float16*)ws; ws += (size_t)3072 * QLR * 2;         //  3.1 MB
    _Float16* wkvuh  = (_Float16*)ws; ws += (size_t)4096 * KVLR * 2;        //  4.2 MB
    _Float16* c_q    = (_Float16*)ws; ws += (size_t)SEQ * QLR * 2;          //  4.2 MB
    _Float16* c_kv   = (_Float16*)ws; ws += (size_t)SEQ * KVLR * 2;         //  4.2 MB
    _Float16* ktmp   = (_Float16*)ws; ws += (size_t)SEQ * RD * 2;           //  0.5 MB
    _Float16* qfin   = (_Float16*)ws; ws += (size_t)SEQ * NHEAD * KDIM * 2; // 25.2 MB
    _Float16* kfin   = (_Float16*)ws; ws += (size_t)SEQ * NHEAD * KDIM * 2; // 25.2 MB
    _Float16* vT     = (_Float16*)ws; ws += (size_t)NHEAD * VD * SEQ * 2;   // 16.8 MB
    _Float16* attn   = x_h;                                                  // alias
    _Float16* wouth  = c_q;                                                  // alias (8.4 MB)

    dim3 blk(256);

    // f16 conversions
    cvt_plain<<<dim3(4096), blk, 0, stream>>>(x, x_h, SEQ * EMBED / 8);
    cvt_down <<<dim3(1152), blk, 0, stream>>>(wqd, wkvd, wkr, wdownh);
    cvt_qup  <<<dim3(768),  blk, 0, stream>>>(wqu, wqr, wquph);
    cvt_plain<<<dim3(1024), blk, 0, stream>>>(wkvu, wkvuh, 4096 * KVLR / 8);

    // G1: x @ [wqd;wkvd;wkr]^T -> c_q, c_kv, ktmp     (4096 x 1152, K=2048)
    gemm_f16<0><<<dim3(9, 32), blk, 0, stream>>>(
        x_h, wdownh, c_q, c_kv, ktmp, nullptr, SEQ, 1152, EMBED);
    // G2: c_q @ [wqu;wqr]^T -> qfin                   (4096 x 3072, K=512)
    gemm_f16<1><<<dim3(24, 32), blk, 0, stream>>>(
        c_q, wquph, qfin, nullptr, nullptr, nullptr, SEQ, 3072, QLR);
    // G3: c_kv @ wkvu^T -> kfin, vT                   (4096 x 4096, K=512)
    gemm_f16<2><<<dim3(32, 32), blk, 0, stream>>>(
        c_kv, wkvuh, kfin, vT, nullptr, nullptr, SEQ, 4096, KVLR);

    // wout conversion now that c_q/c_kv are dead
    cvt_plain<<<dim3(2048), blk, 0, stream>>>(wout, wouth, EMBED * EMBED / 8);

    // RoPE
    rope_kernel<<<dim3(SEQ), blk, 0, stream>>>(qfin, kfin, ktmp);
    // attention (dual-tile causal flash)
    fattn<<<dim3(32, NHEAD), blk, 0, stream>>>(qfin, kfin, vT, attn);
    // G4: attn @ wout^T -> out (f32)                  (4096 x 2048, K=2048)
    gemm_f16<3><<<dim3(16, 32), blk, 0, stream>>>(
        attn, wouth, nullptr, nullptr, nullptr, out, SEQ, EMBED, NHEAD * VD);
}

// Round 3
// 635.222 us; speedup vs baseline: 1.7105x; 1.5723x over previous
//
#include <hip/hip_runtime.h>

// ---------------------------------------------------------------------------
// MLA forward, MI355X (gfx950). FP16 MFMA, f32 accumulate.
// SEQ=4096 EMBED=2048 H=16 QLR=512 KVLR=512 RD=64 VD=128 KD=192
// Round 3: fattn -> 128-row q-tile, 8 waves, swizzled LDS (K reg-staged,
//          V via global_load_lds w/ pre-swizzled source), kfin per-head.
// ---------------------------------------------------------------------------

#define SEQ   4096
#define EMBED 2048
#define NHEAD 16
#define QLR   512
#define KVLR  512
#define RD    64
#define VD    128
#define KDIM  192

typedef __attribute__((ext_vector_type(8))) _Float16 half8;
typedef __attribute__((ext_vector_type(4))) _Float16 half4;
typedef __attribute__((ext_vector_type(4))) float    f32x4;

__device__ __forceinline__ void gload16(void* lds, const void* g) {
    __builtin_amdgcn_global_load_lds(
        (const __attribute__((address_space(1))) void*)g,
        (__attribute__((address_space(3))) void*)lds, 16, 0, 0);
}

// ---------------- f32 -> f16 conversion kernels ----------------------------
__global__ __launch_bounds__(256) void cvt_plain(const float* __restrict__ s,
                                                 _Float16* __restrict__ d, int n8) {
    const int i = blockIdx.x * 256 + threadIdx.x;
    if (i >= n8) return;
    const float4 a = reinterpret_cast<const float4*>(s)[i * 2];
    const float4 b = reinterpret_cast<const float4*>(s)[i * 2 + 1];
    half8 r;
    r[0] = (_Float16)a.x; r[1] = (_Float16)a.y; r[2] = (_Float16)a.z; r[3] = (_Float16)a.w;
    r[4] = (_Float16)b.x; r[5] = (_Float16)b.y; r[6] = (_Float16)b.z; r[7] = (_Float16)b.w;
    reinterpret_cast<half8*>(d)[i] = r;
}

__global__ __launch_bounds__(256) void cvt_down(const float* __restrict__ wqd,
                                                const float* __restrict__ wkvd,
                                                const float* __restrict__ wkr,
                                                _Float16* __restrict__ dst) {
    const int i = blockIdx.x * 256 + threadIdx.x;
    if (i >= 1152 * 2048 / 8) return;
    const int e = i * 8, row = e >> 11, col = e & 2047;
    const float* src = row < 512  ? wqd  + (size_t)row * 2048 + col
                     : row < 1024 ? wkvd + (size_t)(row - 512) * 2048 + col
                     : row < 1088 ? wkr  + (size_t)(row - 1024) * 2048 + col
                                  : nullptr;
    half8 r = {};
    if (src) {
        const float4 a = reinterpret_cast<const float4*>(src)[0];
        const float4 b = reinterpret_cast<const float4*>(src)[1];
        r[0] = (_Float16)a.x; r[1] = (_Float16)a.y; r[2] = (_Float16)a.z; r[3] = (_Float16)a.w;
        r[4] = (_Float16)b.x; r[5] = (_Float16)b.y; r[6] = (_Float16)b.z; r[7] = (_Float16)b.w;
    }
    reinterpret_cast<half8*>(dst)[i] = r;
}

__global__ __launch_bounds__(256) void cvt_qup(const float* __restrict__ wqu,
                                               const float* __restrict__ wqr,
                                               _Float16* __restrict__ dst) {
    const int i = blockIdx.x * 256 + threadIdx.x;
    if (i >= 3072 * 512 / 8) return;
    const int e = i * 8, row = e >> 9, col = e & 511;
    const float* src = row < 2048 ? wqu + (size_t)row * 512 + col
                                  : wqr + (size_t)(row - 2048) * 512 + col;
    const float4 a = reinterpret_cast<const float4*>(src)[0];
    const float4 b = reinterpret_cast<const float4*>(src)[1];
    half8 r;
    r[0] = (_Float16)a.x; r[1] = (_Float16)a.y; r[2] = (_Float16)a.z; r[3] = (_Float16)a.w;
    r[4] = (_Float16)b.x; r[5] = (_Float16)b.y; r[6] = (_Float16)b.z; r[7] = (_Float16)b.w;
    reinterpret_cast<half8*>(dst)[i] = r;
}

// ---------------------------------------------------------------------------
// f16 GEMM, m97 structure (unchanged from round 2 except EPI2 kfin layout).
// EPI 0: split -> c_q | c_kv | ktmp
// EPI 1: q up  -> qfin[s][h*192+d]
// EPI 2: kv    -> kfin[h][s][192] (cols<2048) | vT[h*128+d][s] (else)
// EPI 3: f32 plain
// ---------------------------------------------------------------------------
template <int EPI>
__global__ __launch_bounds__(256) void gemm_f16(const _Float16* __restrict__ A,
                                                const _Float16* __restrict__ B,
                                                _Float16* __restrict__ o0,
                                                _Float16* __restrict__ o1,
                                                _Float16* __restrict__ o2,
                                                float* __restrict__ of,
                                                int M, int N, int K)
{
    __shared__ _Float16 sA[128 * 64];
    __shared__ _Float16 sB[128 * 64];

    const int tid  = threadIdx.x;
    const int wid  = tid >> 6;
    const int lane = tid & 63;
    const int lr   = lane & 15;
    const int lg   = lane >> 4;
    const int row0 = blockIdx.y * 128;
    const int col0 = blockIdx.x * 128;
    const int war  = (wid >> 1) * 64;
    const int wac  = (wid & 1) * 64;

    const int sr = lane >> 3;
    const int sk = (lane & 7) * 8;
    const _Float16* Ab = A + (size_t)(row0 + wid * 8 + sr) * K + sk;
    const _Float16* Bb = B + (size_t)(col0 + wid * 8 + sr) * K + sk;

    f32x4 acc[4][4] = {};

    for (int k0 = 0; k0 < K; k0 += 64) {
#pragma unroll
        for (int i = 0; i < 4; ++i) {
            const int c = i * 4 + wid;
            gload16((char*)sA + c * 1024, Ab + (size_t)i * 32 * K + k0);
            gload16((char*)sB + c * 1024, Bb + (size_t)i * 32 * K + k0);
        }
        __syncthreads();

#pragma unroll
        for (int kk = 0; kk < 64; kk += 32) {
            half8 a[4], b[4];
#pragma unroll
            for (int i = 0; i < 4; ++i)
                a[i] = *reinterpret_cast<const half8*>(&sA[(war + i * 16 + lr) * 64 + kk + lg * 8]);
#pragma unroll
            for (int j = 0; j < 4; ++j)
                b[j] = *reinterpret_cast<const half8*>(&sB[(wac + j * 16 + lr) * 64 + kk + lg * 8]);
            __builtin_amdgcn_s_setprio(1);
#pragma unroll
            for (int i = 0; i < 4; ++i)
#pragma unroll
                for (int j = 0; j < 4; ++j)
                    acc[i][j] = __builtin_amdgcn_mfma_f32_16x16x32_f16(a[i], b[j], acc[i][j], 0, 0, 0);
            __builtin_amdgcn_s_setprio(0);
        }
        __syncthreads();
    }

#pragma unroll
    for (int i = 0; i < 4; ++i)
#pragma unroll
        for (int j = 0; j < 4; ++j) {
            const int grow0 = row0 + war + i * 16 + lg * 4;
            const int gcol  = col0 + wac + j * 16 + lr;
            if constexpr (EPI == 2) {
                if (gcol >= 2048) {
                    half4 pv;
#pragma unroll
                    for (int r = 0; r < 4; ++r) pv[r] = (_Float16)acc[i][j][r];
                    *reinterpret_cast<half4*>(&o1[(size_t)(gcol - 2048) * SEQ + grow0]) = pv;
                    continue;
                }
            }
#pragma unroll
            for (int r = 0; r < 4; ++r) {
                const int grow = grow0 + r;
                const float v = acc[i][j][r];
                if constexpr (EPI == 0) {
                    if (gcol < 512)       o0[(size_t)grow * 512 + gcol] = (_Float16)v;
                    else if (gcol < 1024) o1[(size_t)grow * 512 + gcol - 512] = (_Float16)v;
                    else if (gcol < 1088) o2[(size_t)grow * 64 + gcol - 1024] = (_Float16)v;
                } else if constexpr (EPI == 1) {
                    if (gcol < 2048)
                        o0[(size_t)grow * (NHEAD * KDIM) + (gcol >> 7) * KDIM + (gcol & 127)] = (_Float16)v;
                    else {
                        const int c = gcol - 2048;
                        o0[(size_t)grow * (NHEAD * KDIM) + (c >> 6) * KDIM + VD + (c & 63)] = (_Float16)v;
                    }
                } else if constexpr (EPI == 2) {
                    // kfin per-head: [h][s][192]
                    o0[((size_t)(gcol >> 7) * SEQ + grow) * KDIM + (gcol & 127)] = (_Float16)v;
                } else {
                    of[(size_t)grow * N + gcol] = v;
                }
            }
        }
}

// ---------------------------------------------------------------------------
// RoPE: q in place (qfin[s][h*192+...]); shared k -> kfin[h][s][128+...].
// ---------------------------------------------------------------------------
__global__ __launch_bounds__(256) void rope_kernel(_Float16* __restrict__ qf,
                                                   _Float16* __restrict__ kf,
                                                   const _Float16* __restrict__ ktmp)
{
    __shared__ float s_sin[32], s_cos[32];
    const int s   = blockIdx.x;
    const int tid = threadIdx.x;
    if (tid < 32) {
        const double inv = exp(-(double)tid * (log(10000.0) / 32.0));
        const double ang = (double)s * inv;
        s_sin[tid] = (float)sin(ang);
        s_cos[tid] = (float)cos(ang);
    }
    __syncthreads();

    for (int p = tid; p < NHEAD * 32; p += 256) {
        const int h = p >> 5, i = p & 31;
        const size_t base = (size_t)s * (NHEAD * KDIM) + h * KDIM + VD;
        const float x1 = (float)qf[base + i];
        const float x2 = (float)qf[base + 32 + i];
        const float cs = s_cos[i], sn = s_sin[i];
        qf[base + i]      = (_Float16)(x1 * cs - x2 * sn);
        qf[base + 32 + i] = (_Float16)(x2 * cs + x1 * sn);
    }
    if (tid < 32) {
        const int i = tid;
        const float x1 = (float)ktmp[(size_t)s * RD + i];
        const float x2 = (float)ktmp[(size_t)s * RD + 32 + i];
        const float cs = s_cos[i], sn = s_sin[i];
        const _Float16 r1 = (_Float16)(x1 * cs - x2 * sn);
        const _Float16 r2 = (_Float16)(x2 * cs + x1 * sn);
#pragma unroll
        for (int h = 0; h < NHEAD; ++h) {
            const size_t base = ((size_t)h * SEQ + s) * KDIM + VD;
            kf[base + i]      = r1;
            kf[base + 32 + i] = r2;
        }
    }
}

// ---------------------------------------------------------------------------
// Causal flash attention: block = (q-tile of 128 rows, head), 8 waves x 16 rows.
// KV step 64. K: reg-staged into XOR-swizzled LDS [64][192] (granule ^= row&7).
// V^T: global_load_lds into [128][64] with pre-swizzled global source.
// P: per-wave XOR-swizzled [16][64]. All MFMA-frag LDS reads conflict-free.
// ---------------------------------------------------------------------------
__global__ __launch_bounds__(512, 4) void fattn(const _Float16* __restrict__ qf,
                                                const _Float16* __restrict__ kf,
                                                const _Float16* __restrict__ vT,
                                                _Float16* __restrict__ attn)
{
    __shared__ _Float16 sK[64 * 192];    // 24 KB, swizzled
    __shared__ _Float16 sVt[128 * 64];   // 16 KB, swizzled
    __shared__ _Float16 sP[8 * 16 * 64]; // 16 KB, swizzled, per-wave 2KB

    const int qt = 31 - blockIdx.x;      // heavy tiles first
    const int h  = blockIdx.y;
    const int q0 = qt * 128;

    const int tid  = threadIdx.x;
    const int wid  = tid >> 6;
    const int lane = tid & 63;
    const int lr   = lane & 15;
    const int lg   = lane >> 4;

    const float scale = 0.0721687836487032f;   // 1/sqrt(192)

    // ---- K staging constants: 3 chunks/thread, c = tid + i*512 ----
    int krow[3], kgr[3], klds[3];
    const _Float16* ksrc[3];
#pragma unroll
    for (int i = 0; i < 3; ++i) {
        const int c = tid + i * 512;
        krow[i] = c / 24;
        kgr[i]  = c % 24;
        klds[i] = krow[i] * 384 + ((kgr[i] ^ (krow[i] & 7)) << 4);      // byte addr
        ksrc[i] = kf + ((size_t)h * SEQ + krow[i]) * KDIM + kgr[i] * 8; // + j0*KDIM
    }
    // ---- V staging: 2 gload16/wave; dbase = wid*16 + i*8 ----
    const _Float16* vsrc[2];
    int vlds[2];
#pragma unroll
    for (int i = 0; i < 2; ++i) {
        const int dbase = wid * 16 + i * 8;
        const int d = dbase + (lane >> 3);
        vsrc[i] = vT + ((size_t)h * VD + d) * SEQ + (((lane & 7) ^ (lane >> 3)) << 3); // + j0
        vlds[i] = dbase * 128;   // byte base (wave-uniform)
    }

    // ---- Q fragments: 16 rows per wave, k-slots at kk*32 + lg*8 ----
    half8 qfr[6];
    {
        const int qrow = q0 + wid * 16 + lr;
        const _Float16* qb = qf + (size_t)qrow * (NHEAD * KDIM) + h * KDIM + lg * 8;
#pragma unroll
        for (int kk = 0; kk < 6; ++kk)
            qfr[kk] = *reinterpret_cast<const half8*>(qb + kk * 32);
    }

    f32x4 o[8] = {};
    float m_[4], l_[4];
#pragma unroll
    for (int r = 0; r < 4; ++r) { m_[r] = -1e30f; l_[r] = 0.0f; }

    const int nt = 2 * qt + 2;
    for (int t = 0; t < nt; ++t) {
        const int j0 = t * 64;

        // ---- stage K (reg -> swizzled LDS) + V (gload, pre-swizzled src) ----
#pragma unroll
        for (int i = 0; i < 3; ++i) {
            const half8 kv = *reinterpret_cast<const half8*>(ksrc[i] + (size_t)j0 * KDIM);
            *reinterpret_cast<half8*>((char*)sK + klds[i]) = kv;
        }
#pragma unroll
        for (int i = 0; i < 2; ++i)
            gload16((char*)sVt + vlds[i], vsrc[i] + j0);
        __syncthreads();

        // ---- S = Q K^T ----
        f32x4 s2[4];
        __builtin_amdgcn_s_setprio(1);
#pragma unroll
        for (int jt = 0; jt < 4; ++jt) {
            f32x4 a = {};
#pragma unroll
            for (int kk = 0; kk < 6; ++kk) {
                const int row = jt * 16 + lr;
                const half8 bK = *reinterpret_cast<const half8*>(
                    (char*)sK + row * 384 + (((kk * 4 + lg) ^ (lr & 7)) << 4));
                a = __builtin_amdgcn_mfma_f32_16x16x32_f16(qfr[kk], bK, a, 0, 0, 0);
            }
            s2[jt] = a;
        }
        __builtin_amdgcn_s_setprio(0);

        // ---- scale + causal mask + online softmax ----
        const int qrow_g = q0 + wid * 16 + lg * 4;   // + r
        const bool needmask = (j0 + 63) > (q0 + wid * 16);
        float rmax[4];
#pragma unroll
        for (int r = 0; r < 4; ++r) rmax[r] = -1e30f;
        if (needmask) {
#pragma unroll
            for (int jt = 0; jt < 4; ++jt) {
                const int jg = j0 + jt * 16 + lr;
#pragma unroll
                for (int r = 0; r < 4; ++r) {
                    float v = s2[jt][r] * scale;
                    if (jg > qrow_g + r) v = -1e30f;
                    s2[jt][r] = v;
                    rmax[r] = fmaxf(rmax[r], v);
                }
            }
        } else {
#pragma unroll
            for (int jt = 0; jt < 4; ++jt)
#pragma unroll
                for (int r = 0; r < 4; ++r) {
                    const float v = s2[jt][r] * scale;
                    s2[jt][r] = v;
                    rmax[r] = fmaxf(rmax[r], v);
                }
        }
#pragma unroll
        for (int r = 0; r < 4; ++r)
            for (int msk = 1; msk < 16; msk <<= 1)
                rmax[r] = fmaxf(rmax[r], __shfl_xor(rmax[r], msk, 64));

        float alpha[4], rsum[4];
#pragma unroll
        for (int r = 0; r < 4; ++r) {
            const float mn = fmaxf(m_[r], rmax[r]);
            alpha[r] = __expf(m_[r] - mn);
            m_[r] = mn;
            rsum[r] = 0.0f;
        }
#pragma unroll
        for (int jt = 0; jt < 4; ++jt)
#pragma unroll
            for (int r = 0; r < 4; ++r) {
                const float pv = __expf(s2[jt][r] - m_[r]);
                s2[jt][r] = pv;
                rsum[r] += pv;
            }
#pragma unroll
        for (int r = 0; r < 4; ++r) {
            for (int msk = 1; msk < 16; msk <<= 1)
                rsum[r] += __shfl_xor(rsum[r], msk, 64);
            l_[r] = l_[r] * alpha[r] + rsum[r];
        }
#pragma unroll
        for (int dt = 0; dt < 8; ++dt)
#pragma unroll
            for (int r = 0; r < 4; ++r) o[dt][r] *= alpha[r];

        // ---- P -> per-wave swizzled LDS ----
#pragma unroll
        for (int jt = 0; jt < 4; ++jt)
#pragma unroll
            for (int r = 0; r < 4; ++r) {
                const int row = lg * 4 + r;
                const int g   = jt * 2 + (lr >> 3);
                ((_Float16*)((char*)sP + wid * 2048 + row * 128
                             + ((g ^ (row & 7)) << 4)))[lr & 7] = (_Float16)s2[jt][r];
            }
        asm volatile("s_waitcnt lgkmcnt(0)" ::: "memory");
        __builtin_amdgcn_sched_barrier(0);

        // ---- O += P V ----
        __builtin_amdgcn_s_setprio(1);
#pragma unroll
        for (int kk = 0; kk < 2; ++kk) {
            const half8 pa = *reinterpret_cast<const half8*>(
                (char*)sP + wid * 2048 + lr * 128 + (((kk * 4 + lg) ^ (lr & 7)) << 4));
#pragma unroll
            for (int dt = 0; dt < 8; ++dt) {
                const int row = dt * 16 + lr;
                const half8 bv = *reinterpret_cast<const half8*>(
                    (char*)sVt + row * 128 + (((kk * 4 + lg) ^ (lr & 7)) << 4));
                o[dt] = __builtin_amdgcn_mfma_f32_16x16x32_f16(pa, bv, o[dt], 0, 0, 0);
            }
        }
        __builtin_amdgcn_s_setprio(0);
        __syncthreads();
    }

    // ---- normalize + store ----
#pragma unroll
    for (int r = 0; r < 4; ++r) {
        const float inv_l = 1.0f / l_[r];
        const int grow = q0 + wid * 16 + lg * 4 + r;
#pragma unroll
        for (int dt = 0; dt < 8; ++dt)
            attn[(size_t)grow * (NHEAD * VD) + h * VD + dt * 16 + lr] =
                (_Float16)(o[dt][r] * inv_l);
    }
}

// ---------------------------------------------------------------------------
extern "C" void kernel_launch(void* const* d_in, const int* in_sizes, int n_in,
                              void* d_out, int out_size, void* d_ws, size_t ws_size,
                              hipStream_t stream)
{
    (void)in_sizes; (void)n_in; (void)out_size; (void)ws_size;
    const float* x    = (const float*)d_in[0];
    const float* wqd  = (const float*)d_in[2];
    const float* wqu  = (const float*)d_in[3];
    const float* wqr  = (const float*)d_in[4];
    const float* wkvd = (const float*)d_in[5];
    const float* wkvu = (const float*)d_in[6];
    const float* wkr  = (const float*)d_in[7];
    const float* wout = (const float*)d_in[8];
    float* out = (float*)d_out;

    char* ws = (char*)d_ws;
    _Float16* x_h    = (_Float16*)ws; ws += (size_t)SEQ * EMBED * 2;
    _Float16* wdownh = (_Float16*)ws; ws += (size_t)1152 * EMBED * 2;
    _Float16* wquph  = (_Float16*)ws; ws += (size_t)3072 * QLR * 2;
    _Float16* wkvuh  = (_Float16*)ws; ws += (size_t)4096 * KVLR * 2;
    _Float16* c_q    = (_Float16*)ws; ws += (size_t)SEQ * QLR * 2;
    _Float16* c_kv   = (_Float16*)ws; ws += (size_t)SEQ * KVLR * 2;
    _Float16* ktmp   = (_Float16*)ws; ws += (size_t)SEQ * RD * 2;
    _Float16* qfin   = (_Float16*)ws; ws += (size_t)SEQ * NHEAD * KDIM * 2;
    _Float16* kfin   = (_Float16*)ws; ws += (size_t)SEQ * NHEAD * KDIM * 2;  // [h][s][192]
    _Float16* vT     = (_Float16*)ws; ws += (size_t)NHEAD * VD * SEQ * 2;
    _Float16* attn   = x_h;      // alias (x_h dead after G1)
    _Float16* wouth  = c_q;      // alias (c_q dead after G2)

    dim3 blk(256);

    cvt_plain<<<dim3(4096), blk, 0, stream>>>(x, x_h, SEQ * EMBED / 8);
    cvt_down <<<dim3(1152), blk, 0, stream>>>(wqd, wkvd, wkr, wdownh);
    cvt_qup  <<<dim3(768),  blk, 0, stream>>>(wqu, wqr, wquph);
    cvt_plain<<<dim3(1024), blk, 0, stream>>>(wkvu, wkvuh, 4096 * KVLR / 8);

    // G1: x @ [wqd;wkvd;wkr]^T -> c_q, c_kv, ktmp
    gemm_f16<0><<<dim3(9, 32), blk, 0, stream>>>(
        x_h, wdownh, c_q, c_kv, ktmp, nullptr, SEQ, 1152, EMBED);
    // G2: c_q @ [wqu;wqr]^T -> qfin
    gemm_f16<1><<<dim3(24, 32), blk, 0, stream>>>(
        c_q, wquph, qfin, nullptr, nullptr, nullptr, SEQ, 3072, QLR);
    // G3: c_kv @ wkvu^T -> kfin (per-head), vT
    gemm_f16<2><<<dim3(32, 32), blk, 0, stream>>>(
        c_kv, wkvuh, kfin, vT, nullptr, nullptr, SEQ, 4096, KVLR);

    cvt_plain<<<dim3(2048), blk, 0, stream>>>(wout, wouth, EMBED * EMBED / 8);

    rope_kernel<<<dim3(SEQ), blk, 0, stream>>>(qfin, kfin, ktmp);
    fattn<<<dim3(32, NHEAD), dim3(512), 0, stream>>>(qfin, kfin, vT, attn);
    // G4: attn @ wout^T -> out (f32)
    gemm_f16<3><<<dim3(16, 32), blk, 0, stream>>>(
        attn, wouth, nullptr, nullptr, nullptr, out, SEQ, EMBED, NHEAD * VD);
}

// Round 4
// 372.911 us; speedup vs baseline: 2.9137x; 1.7034x over previous
//
#include <hip/hip_runtime.h>

// ---------------------------------------------------------------------------
// MLA forward, MI355X (gfx950). FP16 MFMA, f32 accumulate.
// SEQ=4096 EMBED=2048 H=16 QLR=512 KVLR=512 RD=64 VD=128 KD=192
// Round 4: fattn double-buffered 2-phase pipeline (gload_lds for K and V,
//          pre-swizzled sources), global heavy-first dispatch, defer-max.
// ---------------------------------------------------------------------------

#define SEQ   4096
#define EMBED 2048
#define NHEAD 16
#define QLR   512
#define KVLR  512
#define RD    64
#define VD    128
#define KDIM  192

typedef __attribute__((ext_vector_type(8))) _Float16 half8;
typedef __attribute__((ext_vector_type(4))) _Float16 half4;
typedef __attribute__((ext_vector_type(4))) float    f32x4;

__device__ __forceinline__ void gload16(void* lds, const void* g) {
    __builtin_amdgcn_global_load_lds(
        (const __attribute__((address_space(1))) void*)g,
        (__attribute__((address_space(3))) void*)lds, 16, 0, 0);
}

// ---------------- f32 -> f16 conversion kernels ----------------------------
__global__ __launch_bounds__(256) void cvt_plain(const float* __restrict__ s,
                                                 _Float16* __restrict__ d, int n8) {
    const int i = blockIdx.x * 256 + threadIdx.x;
    if (i >= n8) return;
    const float4 a = reinterpret_cast<const float4*>(s)[i * 2];
    const float4 b = reinterpret_cast<const float4*>(s)[i * 2 + 1];
    half8 r;
    r[0] = (_Float16)a.x; r[1] = (_Float16)a.y; r[2] = (_Float16)a.z; r[3] = (_Float16)a.w;
    r[4] = (_Float16)b.x; r[5] = (_Float16)b.y; r[6] = (_Float16)b.z; r[7] = (_Float16)b.w;
    reinterpret_cast<half8*>(d)[i] = r;
}

__global__ __launch_bounds__(256) void cvt_down(const float* __restrict__ wqd,
                                                const float* __restrict__ wkvd,
                                                const float* __restrict__ wkr,
                                                _Float16* __restrict__ dst) {
    const int i = blockIdx.x * 256 + threadIdx.x;
    if (i >= 1152 * 2048 / 8) return;
    const int e = i * 8, row = e >> 11, col = e & 2047;
    const float* src = row < 512  ? wqd  + (size_t)row * 2048 + col
                     : row < 1024 ? wkvd + (size_t)(row - 512) * 2048 + col
                     : row < 1088 ? wkr  + (size_t)(row - 1024) * 2048 + col
                                  : nullptr;
    half8 r = {};
    if (src) {
        const float4 a = reinterpret_cast<const float4*>(src)[0];
        const float4 b = reinterpret_cast<const float4*>(src)[1];
        r[0] = (_Float16)a.x; r[1] = (_Float16)a.y; r[2] = (_Float16)a.z; r[3] = (_Float16)a.w;
        r[4] = (_Float16)b.x; r[5] = (_Float16)b.y; r[6] = (_Float16)b.z; r[7] = (_Float16)b.w;
    }
    reinterpret_cast<half8*>(dst)[i] = r;
}

__global__ __launch_bounds__(256) void cvt_qup(const float* __restrict__ wqu,
                                               const float* __restrict__ wqr,
                                               _Float16* __restrict__ dst) {
    const int i = blockIdx.x * 256 + threadIdx.x;
    if (i >= 3072 * 512 / 8) return;
    const int e = i * 8, row = e >> 9, col = e & 511;
    const float* src = row < 2048 ? wqu + (size_t)row * 512 + col
                                  : wqr + (size_t)(row - 2048) * 512 + col;
    const float4 a = reinterpret_cast<const float4*>(src)[0];
    const float4 b = reinterpret_cast<const float4*>(src)[1];
    half8 r;
    r[0] = (_Float16)a.x; r[1] = (_Float16)a.y; r[2] = (_Float16)a.z; r[3] = (_Float16)a.w;
    r[4] = (_Float16)b.x; r[5] = (_Float16)b.y; r[6] = (_Float16)b.z; r[7] = (_Float16)b.w;
    reinterpret_cast<half8*>(dst)[i] = r;
}

// ---------------------------------------------------------------------------
// f16 GEMM, m97 structure (unchanged from round 3).
// ---------------------------------------------------------------------------
template <int EPI>
__global__ __launch_bounds__(256) void gemm_f16(const _Float16* __restrict__ A,
                                                const _Float16* __restrict__ B,
                                                _Float16* __restrict__ o0,
                                                _Float16* __restrict__ o1,
                                                _Float16* __restrict__ o2,
                                                float* __restrict__ of,
                                                int M, int N, int K)
{
    __shared__ _Float16 sA[128 * 64];
    __shared__ _Float16 sB[128 * 64];

    const int tid  = threadIdx.x;
    const int wid  = tid >> 6;
    const int lane = tid & 63;
    const int lr   = lane & 15;
    const int lg   = lane >> 4;
    const int row0 = blockIdx.y * 128;
    const int col0 = blockIdx.x * 128;
    const int war  = (wid >> 1) * 64;
    const int wac  = (wid & 1) * 64;

    const int sr = lane >> 3;
    const int sk = (lane & 7) * 8;
    const _Float16* Ab = A + (size_t)(row0 + wid * 8 + sr) * K + sk;
    const _Float16* Bb = B + (size_t)(col0 + wid * 8 + sr) * K + sk;

    f32x4 acc[4][4] = {};

    for (int k0 = 0; k0 < K; k0 += 64) {
#pragma unroll
        for (int i = 0; i < 4; ++i) {
            const int c = i * 4 + wid;
            gload16((char*)sA + c * 1024, Ab + (size_t)i * 32 * K + k0);
            gload16((char*)sB + c * 1024, Bb + (size_t)i * 32 * K + k0);
        }
        __syncthreads();

#pragma unroll
        for (int kk = 0; kk < 64; kk += 32) {
            half8 a[4], b[4];
#pragma unroll
            for (int i = 0; i < 4; ++i)
                a[i] = *reinterpret_cast<const half8*>(&sA[(war + i * 16 + lr) * 64 + kk + lg * 8]);
#pragma unroll
            for (int j = 0; j < 4; ++j)
                b[j] = *reinterpret_cast<const half8*>(&sB[(wac + j * 16 + lr) * 64 + kk + lg * 8]);
            __builtin_amdgcn_s_setprio(1);
#pragma unroll
            for (int i = 0; i < 4; ++i)
#pragma unroll
                for (int j = 0; j < 4; ++j)
                    acc[i][j] = __builtin_amdgcn_mfma_f32_16x16x32_f16(a[i], b[j], acc[i][j], 0, 0, 0);
            __builtin_amdgcn_s_setprio(0);
        }
        __syncthreads();
    }

#pragma unroll
    for (int i = 0; i < 4; ++i)
#pragma unroll
        for (int j = 0; j < 4; ++j) {
            const int grow0 = row0 + war + i * 16 + lg * 4;
            const int gcol  = col0 + wac + j * 16 + lr;
            if constexpr (EPI == 2) {
                if (gcol >= 2048) {
                    half4 pv;
#pragma unroll
                    for (int r = 0; r < 4; ++r) pv[r] = (_Float16)acc[i][j][r];
                    *reinterpret_cast<half4*>(&o1[(size_t)(gcol - 2048) * SEQ + grow0]) = pv;
                    continue;
                }
            }
#pragma unroll
            for (int r = 0; r < 4; ++r) {
                const int grow = grow0 + r;
                const float v = acc[i][j][r];
                if constexpr (EPI == 0) {
                    if (gcol < 512)       o0[(size_t)grow * 512 + gcol] = (_Float16)v;
                    else if (gcol < 1024) o1[(size_t)grow * 512 + gcol - 512] = (_Float16)v;
                    else if (gcol < 1088) o2[(size_t)grow * 64 + gcol - 1024] = (_Float16)v;
                } else if constexpr (EPI == 1) {
                    if (gcol < 2048)
                        o0[(size_t)grow * (NHEAD * KDIM) + (gcol >> 7) * KDIM + (gcol & 127)] = (_Float16)v;
                    else {
                        const int c = gcol - 2048;
                        o0[(size_t)grow * (NHEAD * KDIM) + (c >> 6) * KDIM + VD + (c & 63)] = (_Float16)v;
                    }
                } else if constexpr (EPI == 2) {
                    o0[((size_t)(gcol >> 7) * SEQ + grow) * KDIM + (gcol & 127)] = (_Float16)v;
                } else {
                    of[(size_t)grow * N + gcol] = v;
                }
            }
        }
}

// ---------------------------------------------------------------------------
// RoPE: q in place (qfin[s][h*192+...]); shared k -> kfin[h][s][128+...].
// ---------------------------------------------------------------------------
__global__ __launch_bounds__(256) void rope_kernel(_Float16* __restrict__ qf,
                                                   _Float16* __restrict__ kf,
                                                   const _Float16* __restrict__ ktmp)
{
    __shared__ float s_sin[32], s_cos[32];
    const int s   = blockIdx.x;
    const int tid = threadIdx.x;
    if (tid < 32) {
        const double inv = exp(-(double)tid * (log(10000.0) / 32.0));
        const double ang = (double)s * inv;
        s_sin[tid] = (float)sin(ang);
        s_cos[tid] = (float)cos(ang);
    }
    __syncthreads();

    for (int p = tid; p < NHEAD * 32; p += 256) {
        const int h = p >> 5, i = p & 31;
        const size_t base = (size_t)s * (NHEAD * KDIM) + h * KDIM + VD;
        const float x1 = (float)qf[base + i];
        const float x2 = (float)qf[base + 32 + i];
        const float cs = s_cos[i], sn = s_sin[i];
        qf[base + i]      = (_Float16)(x1 * cs - x2 * sn);
        qf[base + 32 + i] = (_Float16)(x2 * cs + x1 * sn);
    }
    if (tid < 32) {
        const int i = tid;
        const float x1 = (float)ktmp[(size_t)s * RD + i];
        const float x2 = (float)ktmp[(size_t)s * RD + 32 + i];
        const float cs = s_cos[i], sn = s_sin[i];
        const _Float16 r1 = (_Float16)(x1 * cs - x2 * sn);
        const _Float16 r2 = (_Float16)(x2 * cs + x1 * sn);
#pragma unroll
        for (int h = 0; h < NHEAD; ++h) {
            const size_t base = ((size_t)h * SEQ + s) * KDIM + VD;
            kf[base + i]      = r1;
            kf[base + 32 + i] = r2;
        }
    }
}

// ---------------------------------------------------------------------------
// Causal flash attention, double-buffered 2-phase pipeline.
// Block = (q-tile of 128 rows, head), 8 waves x 16 rows. KV step 64.
// K and V^T both staged by global_load_lds with PRE-SWIZZLED global sources
// (LDS dest linear; read side applies the same XOR involution -> 0 conflicts).
// Loop: issue stage(t+1) into buf^1, compute on buf, vmcnt-drain+barrier.
// Dispatch: 1-D grid, qt descending globally (heavy blocks first).
// ---------------------------------------------------------------------------
__global__ __launch_bounds__(512, 2) void fattn(const _Float16* __restrict__ qf,
                                                const _Float16* __restrict__ kf,
                                                const _Float16* __restrict__ vT,
                                                _Float16* __restrict__ attn)
{
    __shared__ _Float16 sK[2][64 * 192];    // 2 x 24 KB
    __shared__ _Float16 sVt[2][128 * 64];   // 2 x 16 KB
    __shared__ _Float16 sP[8 * 16 * 64];    // 16 KB, per-wave 2 KB

    const int idx = blockIdx.x;
    const int qt  = 31 - (idx >> 4);        // heavy first, globally
    const int h   = idx & 15;
    const int q0  = qt * 128;

    const int tid  = threadIdx.x;
    const int wid  = tid >> 6;
    const int lane = tid & 63;
    const int lr   = lane & 15;
    const int lg   = lane >> 4;

    const float scale = 0.0721687836487032f;   // 1/sqrt(192)

    // ---- K staging: 24 chunks of 1KB; chunk c = wid*3+i. LDS linear,
    //      global source pre-swizzled: granule g at row goes to G = g^(row&7).
    const _Float16* ksrc[3];
    int klds[3];
#pragma unroll
    for (int i = 0; i < 3; ++i) {
        const int c  = wid * 3 + i;
        const int gi = c * 64 + lane;           // granule index in tile
        const int row = gi / 24;
        const int g   = gi % 24;
        ksrc[i] = kf + ((size_t)h * SEQ + row) * KDIM + ((g ^ (row & 7)) << 3);
        klds[i] = c * 1024;
    }
    // ---- V staging: 16 chunks; wave covers rows dbase..dbase+15 ----
    const _Float16* vsrc[2];
    int vlds[2];
#pragma unroll
    for (int i = 0; i < 2; ++i) {
        const int dbase = wid * 16 + i * 8;
        const int d = dbase + (lane >> 3);
        vsrc[i] = vT + ((size_t)h * VD + d) * SEQ + (((lane & 7) ^ (lane >> 3)) << 3);
        vlds[i] = dbase * 128;
    }

    // ---- Q fragments: 16 rows per wave ----
    half8 qfr[6];
    {
        const int qrow = q0 + wid * 16 + lr;
        const _Float16* qb = qf + (size_t)qrow * (NHEAD * KDIM) + h * KDIM + lg * 8;
#pragma unroll
        for (int kk = 0; kk < 6; ++kk)
            qfr[kk] = *reinterpret_cast<const half8*>(qb + kk * 32);
    }

    f32x4 o[8] = {};
    float m_[4], l_[4];
#pragma unroll
    for (int r = 0; r < 4; ++r) { m_[r] = -1e30f; l_[r] = 0.0f; }

    const int nt = 2 * qt + 2;

    // prologue: stage tile 0 into buf 0
    {
        const int j0 = 0;
#pragma unroll
        for (int i = 0; i < 3; ++i) gload16((char*)sK[0] + klds[i], ksrc[i] + (size_t)j0 * KDIM);
#pragma unroll
        for (int i = 0; i < 2; ++i) gload16((char*)sVt[0] + vlds[i], vsrc[i] + j0);
    }
    __syncthreads();

    for (int t = 0; t < nt; ++t) {
        const int cur = t & 1;
        const int j0 = t * 64;

        // ---- issue next tile's stage into the other buffer ----
        if (t + 1 < nt) {
            const int jn = j0 + 64;
#pragma unroll
            for (int i = 0; i < 3; ++i) gload16((char*)sK[cur ^ 1] + klds[i], ksrc[i] + (size_t)jn * KDIM);
#pragma unroll
            for (int i = 0; i < 2; ++i) gload16((char*)sVt[cur ^ 1] + vlds[i], vsrc[i] + jn);
        }

        // ---- S = Q K^T ----
        f32x4 s2[4];
        __builtin_amdgcn_s_setprio(1);
#pragma unroll
        for (int jt = 0; jt < 4; ++jt) {
            f32x4 a = {};
#pragma unroll
            for (int kk = 0; kk < 6; ++kk) {
                const int row = jt * 16 + lr;
                const half8 bK = *reinterpret_cast<const half8*>(
                    (char*)sK[cur] + row * 384 + (((kk * 4 + lg) ^ (lr & 7)) << 4));
                a = __builtin_amdgcn_mfma_f32_16x16x32_f16(qfr[kk], bK, a, 0, 0, 0);
            }
            s2[jt] = a;
        }
        __builtin_amdgcn_s_setprio(0);

        // ---- scale + causal mask ----
        const int qrow_g = q0 + wid * 16 + lg * 4;   // + r
        const bool needmask = (j0 + 63) > (q0 + wid * 16);
        float rmax[4];
#pragma unroll
        for (int r = 0; r < 4; ++r) rmax[r] = -1e30f;
        if (needmask) {
#pragma unroll
            for (int jt = 0; jt < 4; ++jt) {
                const int jg = j0 + jt * 16 + lr;
#pragma unroll
                for (int r = 0; r < 4; ++r) {
                    float v = s2[jt][r] * scale;
                    if (jg > qrow_g + r) v = -1e30f;
                    s2[jt][r] = v;
                    rmax[r] = fmaxf(rmax[r], v);
                }
            }
        } else {
#pragma unroll
            for (int jt = 0; jt < 4; ++jt)
#pragma unroll
                for (int r = 0; r < 4; ++r) {
                    const float v = s2[jt][r] * scale;
                    s2[jt][r] = v;
                    rmax[r] = fmaxf(rmax[r], v);
                }
        }
#pragma unroll
        for (int r = 0; r < 4; ++r)
            for (int msk = 1; msk < 16; msk <<= 1)
                rmax[r] = fmaxf(rmax[r], __shfl_xor(rmax[r], msk, 64));

        // ---- online softmax with defer-max (THR=8) ----
        float need = -1e30f;
#pragma unroll
        for (int r = 0; r < 4; ++r) need = fmaxf(need, rmax[r] - m_[r]);

        float rsum[4];
        if (__all(need <= 8.0f)) {
            // stable: keep old max, no O/l rescale
#pragma unroll
            for (int r = 0; r < 4; ++r) rsum[r] = 0.0f;
#pragma unroll
            for (int jt = 0; jt < 4; ++jt)
#pragma unroll
                for (int r = 0; r < 4; ++r) {
                    const float pv = __expf(s2[jt][r] - m_[r]);
                    s2[jt][r] = pv;
                    rsum[r] += pv;
                }
#pragma unroll
            for (int r = 0; r < 4; ++r) {
                for (int msk = 1; msk < 16; msk <<= 1)
                    rsum[r] += __shfl_xor(rsum[r], msk, 64);
                l_[r] += rsum[r];
            }
        } else {
            float alpha[4];
#pragma unroll
            for (int r = 0; r < 4; ++r) {
                const float mn = fmaxf(m_[r], rmax[r]);
                alpha[r] = __expf(m_[r] - mn);
                m_[r] = mn;
                rsum[r] = 0.0f;
            }
#pragma unroll
            for (int jt = 0; jt < 4; ++jt)
#pragma unroll
                for (int r = 0; r < 4; ++r) {
                    const float pv = __expf(s2[jt][r] - m_[r]);
                    s2[jt][r] = pv;
                    rsum[r] += pv;
                }
#pragma unroll
            for (int r = 0; r < 4; ++r) {
                for (int msk = 1; msk < 16; msk <<= 1)
                    rsum[r] += __shfl_xor(rsum[r], msk, 64);
                l_[r] = l_[r] * alpha[r] + rsum[r];
            }
#pragma unroll
            for (int dt = 0; dt < 8; ++dt)
#pragma unroll
                for (int r = 0; r < 4; ++r) o[dt][r] *= alpha[r];
        }

        // ---- P -> per-wave swizzled LDS ----
#pragma unroll
        for (int jt = 0; jt < 4; ++jt)
#pragma unroll
            for (int r = 0; r < 4; ++r) {
                const int row = lg * 4 + r;
                const int g   = jt * 2 + (lr >> 3);
                ((_Float16*)((char*)sP + wid * 2048 + row * 128
                             + ((g ^ (row & 7)) << 4)))[lr & 7] = (_Float16)s2[jt][r];
            }
        asm volatile("s_waitcnt lgkmcnt(0)" ::: "memory");
        __builtin_amdgcn_sched_barrier(0);

        // ---- O += P V ----
        __builtin_amdgcn_s_setprio(1);
#pragma unroll
        for (int kk = 0; kk < 2; ++kk) {
            const half8 pa = *reinterpret_cast<const half8*>(
                (char*)sP + wid * 2048 + lr * 128 + (((kk * 4 + lg) ^ (lr & 7)) << 4));
#pragma unroll
            for (int dt = 0; dt < 8; ++dt) {
                const int row = dt * 16 + lr;
                const half8 bv = *reinterpret_cast<const half8*>(
                    (char*)sVt[cur] + row * 128 + (((kk * 4 + lg) ^ (lr & 7)) << 4));
                o[dt] = __builtin_amdgcn_mfma_f32_16x16x32_f16(pa, bv, o[dt], 0, 0, 0);
            }
        }
        __builtin_amdgcn_s_setprio(0);

        // one drain+barrier per step: next buffer complete, current fully read
        __syncthreads();
    }

    // ---- normalize + store ----
#pragma unroll
    for (int r = 0; r < 4; ++r) {
        const float inv_l = 1.0f / l_[r];
        const int grow = q0 + wid * 16 + lg * 4 + r;
#pragma unroll
        for (int dt = 0; dt < 8; ++dt)
            attn[(size_t)grow * (NHEAD * VD) + h * VD + dt * 16 + lr] =
                (_Float16)(o[dt][r] * inv_l);
    }
}

// ---------------------------------------------------------------------------
extern "C" void kernel_launch(void* const* d_in, const int* in_sizes, int n_in,
                              void* d_out, int out_size, void* d_ws, size_t ws_size,
                              hipStream_t stream)
{
    (void)in_sizes; (void)n_in; (void)out_size; (void)ws_size;
    const float* x    = (const float*)d_in[0];
    const float* wqd  = (const float*)d_in[2];
    const float* wqu  = (const float*)d_in[3];
    const float* wqr  = (const float*)d_in[4];
    const float* wkvd = (const float*)d_in[5];
    const float* wkvu = (const float*)d_in[6];
    const float* wkr  = (const float*)d_in[7];
    const float* wout = (const float*)d_in[8];
    float* out = (float*)d_out;

    char* ws = (char*)d_ws;
    _Float16* x_h    = (_Float16*)ws; ws += (size_t)SEQ * EMBED * 2;
    _Float16* wdownh = (_Float16*)ws; ws += (size_t)1152 * EMBED * 2;
    _Float16* wquph  = (_Float16*)ws; ws += (size_t)3072 * QLR * 2;
    _Float16* wkvuh  = (_Float16*)ws; ws += (size_t)4096 * KVLR * 2;
    _Float16* c_q    = (_Float16*)ws; ws += (size_t)SEQ * QLR * 2;
    _Float16* c_kv   = (_Float16*)ws; ws += (size_t)SEQ * KVLR * 2;
    _Float16* ktmp   = (_Float16*)ws; ws += (size_t)SEQ * RD * 2;
    _Float16* qfin   = (_Float16*)ws; ws += (size_t)SEQ * NHEAD * KDIM * 2;
    _Float16* kfin   = (_Float16*)ws; ws += (size_t)SEQ * NHEAD * KDIM * 2;  // [h][s][192]
    _Float16* vT     = (_Float16*)ws; ws += (size_t)NHEAD * VD * SEQ * 2;
    _Float16* attn   = x_h;      // alias (x_h dead after G1)
    _Float16* wouth  = c_q;      // alias (c_q dead after G2)

    dim3 blk(256);

    cvt_plain<<<dim3(4096), blk, 0, stream>>>(x, x_h, SEQ * EMBED / 8);
    cvt_down <<<dim3(1152), blk, 0, stream>>>(wqd, wkvd, wkr, wdownh);
    cvt_qup  <<<dim3(768),  blk, 0, stream>>>(wqu, wqr, wquph);
    cvt_plain<<<dim3(1024), blk, 0, stream>>>(wkvu, wkvuh, 4096 * KVLR / 8);

    // G1: x @ [wqd;wkvd;wkr]^T -> c_q, c_kv, ktmp
    gemm_f16<0><<<dim3(9, 32), blk, 0, stream>>>(
        x_h, wdownh, c_q, c_kv, ktmp, nullptr, SEQ, 1152, EMBED);
    // G2: c_q @ [wqu;wqr]^T -> qfin
    gemm_f16<1><<<dim3(24, 32), blk, 0, stream>>>(
        c_q, wquph, qfin, nullptr, nullptr, nullptr, SEQ, 3072, QLR);
    // G3: c_kv @ wkvu^T -> kfin (per-head), vT
    gemm_f16<2><<<dim3(32, 32), blk, 0, stream>>>(
        c_kv, wkvuh, kfin, vT, nullptr, nullptr, SEQ, 4096, KVLR);

    cvt_plain<<<dim3(2048), blk, 0, stream>>>(wout, wouth, EMBED * EMBED / 8);

    rope_kernel<<<dim3(SEQ), blk, 0, stream>>>(qfin, kfin, ktmp);
    fattn<<<dim3(512), dim3(512), 0, stream>>>(qfin, kfin, vT, attn);
    // G4: attn @ wout^T -> out (f32)
    gemm_f16<3><<<dim3(16, 32), blk, 0, stream>>>(
        attn, wouth, nullptr, nullptr, nullptr, out, SEQ, EMBED, NHEAD * VD);
}